// Round 19
// baseline (70.519 us; speedup 1.0000x reference)
//
#include <hip/hip_runtime.h>

#define B 4
#define T 256
#define S 512
#define H 512
#define BT (B*T)          // 1024

// 2 * log2(e): projections are prescaled so exp2 replaces exp in tanh.
#define PRESCALE 2.8853900817779268f
#define LOG2E 1.4426950408889634f
#define QCLAMP 15.0f      // clamp exp2 arg: ab <= 2^30, den (4-way) <= 2^122

typedef unsigned short u16;
typedef __attribute__((ext_vector_type(8))) short bf16x8;   // 8 bf16 in 4 VGPRs
typedef __attribute__((ext_vector_type(4))) float f32x4;

#if __has_builtin(__builtin_amdgcn_exp2f)
#define EXP2(x) __builtin_amdgcn_exp2f(x)
#else
#define EXP2(x) exp2f(x)
#endif

__device__ __forceinline__ u16 f2bf(float x) {              // RNE fp32->bf16
    unsigned u = __float_as_uint(x);
    u = u + 0x7FFFu + ((u >> 16) & 1u);
    return (u16)(u >> 16);
}

// split 8 fp32 -> bf16 hi (truncated) + bf16 lo (RNE of residual).
__device__ __forceinline__ void split8(float4 f0, float4 f1, bf16x8& hi, bf16x8& lo) {
    float x[8] = {f0.x, f0.y, f0.z, f0.w, f1.x, f1.y, f1.z, f1.w};
    #pragma unroll
    for (int i = 0; i < 8; ++i) {
        unsigned u = __float_as_uint(x[i]);
        unsigned h = u & 0xFFFF0000u;
        hi[i] = (short)(h >> 16);
        lo[i] = (short)f2bf(x[i] - __uint_as_float(h));
    }
}

// ---------------------------------------------------------------------------
// K1: MFMA projection GEMM (fused fp32->bf16 hi/lo split, exp2 epilogue).
//   blockIdx.y <  48: projection tiles (q rows -> abuf; k rows -> bT4)
//   blockIdx.y >= 48: enc transpose+split tiles -> encT_hi/lo[b][h][s]
// ---------------------------------------------------------------------------
__global__ __launch_bounds__(256) void mfma_proj(
    const float* __restrict__ dh, const float* __restrict__ enc,
    const float* __restrict__ W1, const float* __restrict__ W2,
    const float* __restrict__ b1, const float* __restrict__ b2,
    float* __restrict__ abuf, float* __restrict__ bT4,
    u16* __restrict__ encT_hi, u16* __restrict__ encT_lo)
{
    __shared__ u16 lds[4 * 4096];   // 32 KB; transpose path reuses as f32[64][65]

    const int tid   = threadIdx.x;
    const int n0    = blockIdx.x * 64;
    const int mTile = blockIdx.y;           // 0..79

    if (mTile >= 48) {
        // ---- enc transpose + split:  enc[b][s][h] -> encT[b][h][s] ----
        float (*TTf)[65] = reinterpret_cast<float(*)[65]>(lds);
        const int ty = mTile - 48;   // 0..31
        const int bb = ty >> 3;      // batch
        const int st = ty & 7;       // s-tile
        const int c64 = tid & 63;
        const int r4  = tid >> 6;
        #pragma unroll
        for (int rr = 0; rr < 16; ++rr) {
            const int r = rr * 4 + r4;
            TTf[r][c64] = enc[((size_t)(bb * S + st * 64 + r)) * H + n0 + c64];
        }
        __syncthreads();
        const int hr = tid >> 2;           // 0..63 (h within tile)
        const int sq = (tid & 3) * 16;     // 16 s per thread
        u16* ehp = encT_hi + ((size_t)(bb * H + n0 + hr)) * S + st * 64 + sq;
        u16* elp = encT_lo + ((size_t)(bb * H + n0 + hr)) * S + st * 64 + sq;
        #pragma unroll
        for (int j4 = 0; j4 < 4; ++j4) {
            ushort4 hv, lv;
            #pragma unroll
            for (int jj = 0; jj < 4; ++jj) {
                float x = TTf[sq + j4 * 4 + jj][hr];
                unsigned u = __float_as_uint(x);
                unsigned hb = u & 0xFFFF0000u;
                u16 hh = (u16)(hb >> 16);
                u16 ll = f2bf(x - __uint_as_float(hb));
                if (jj == 0) { hv.x = hh; lv.x = ll; }
                else if (jj == 1) { hv.y = hh; lv.y = ll; }
                else if (jj == 2) { hv.z = hh; lv.z = ll; }
                else { hv.w = hh; lv.w = ll; }
            }
            *(ushort4*)&ehp[j4 * 4] = hv;
            *(ushort4*)&elp[j4 * 4] = lv;
        }
        return;
    }

    const int lane  = tid & 63;
    const int w     = tid >> 6;
    const int mbase = mTile * 64;
    const bool is_q = (mTile < 16);

    const float* Asrc = is_q ? dh : enc;
    const float* Wsrc = is_q ? W1 : W2;
    const int arow = is_q ? mbase : (mbase - 1024);

    const int wm = (w & 1) * 32;
    const int wn = (w >> 1) * 32;

    const int r0  = tid >> 3;               // staging row 0..31 (second: +32)
    const int kc0 = tid & 7;                // staging k-chunk

    f32x4 acc[2][2] = {};                   // [ms][ns]

    for (int kb = 0; kb < 8; ++kb) {
        const int k0 = kb * 64 + kc0 * 8;
        const size_t ga0 = (size_t)(arow + r0) * 512 + k0;
        const size_t ga1 = (size_t)(arow + r0 + 32) * 512 + k0;
        const size_t gw0 = (size_t)(n0 + r0) * 512 + k0;
        const size_t gw1 = (size_t)(n0 + r0 + 32) * 512 + k0;
        bf16x8 ah0, al0, ah1, al1, wh0, wl0, wh1, wl1;
        split8(*(const float4*)&Asrc[ga0], *(const float4*)&Asrc[ga0 + 4], ah0, al0);
        split8(*(const float4*)&Asrc[ga1], *(const float4*)&Asrc[ga1 + 4], ah1, al1);
        split8(*(const float4*)&Wsrc[gw0], *(const float4*)&Wsrc[gw0 + 4], wh0, wl0);
        split8(*(const float4*)&Wsrc[gw1], *(const float4*)&Wsrc[gw1 + 4], wh1, wl1);
        __syncthreads();
        const int sw  = (kc0 ^ (r0 & 7)) << 3;       // (r0+32)&7 == r0&7
        const int s0o = r0 * 64 + sw;
        const int s1o = (r0 + 32) * 64 + sw;
        *(bf16x8*)&lds[0 * 4096 + s0o] = ah0;  *(bf16x8*)&lds[0 * 4096 + s1o] = ah1;
        *(bf16x8*)&lds[1 * 4096 + s0o] = al0;  *(bf16x8*)&lds[1 * 4096 + s1o] = al1;
        *(bf16x8*)&lds[2 * 4096 + s0o] = wh0;  *(bf16x8*)&lds[2 * 4096 + s1o] = wh1;
        *(bf16x8*)&lds[3 * 4096 + s0o] = wl0;  *(bf16x8*)&lds[3 * 4096 + s1o] = wl1;
        __syncthreads();

        #pragma unroll
        for (int ks = 0; ks < 2; ++ks) {
            const int kg = ks * 4 + (lane >> 4);     // k-chunk 0..7
            bf16x8 amh[2], aml[2], bnh[2], bnl[2];
            #pragma unroll
            for (int ms = 0; ms < 2; ++ms) {
                const int row = wm + ms * 16 + (lane & 15);
                const int off = row * 64 + ((kg ^ (row & 7)) << 3);
                amh[ms] = *(const bf16x8*)&lds[0 * 4096 + off];
                aml[ms] = *(const bf16x8*)&lds[1 * 4096 + off];
            }
            #pragma unroll
            for (int ns = 0; ns < 2; ++ns) {
                const int row = wn + ns * 16 + (lane & 15);
                const int off = row * 64 + ((kg ^ (row & 7)) << 3);
                bnh[ns] = *(const bf16x8*)&lds[2 * 4096 + off];
                bnl[ns] = *(const bf16x8*)&lds[3 * 4096 + off];
            }
            #pragma unroll
            for (int ms = 0; ms < 2; ++ms)
                #pragma unroll
                for (int ns = 0; ns < 2; ++ns) {
                    acc[ms][ns] = __builtin_amdgcn_mfma_f32_16x16x32_bf16(amh[ms], bnh[ns], acc[ms][ns], 0, 0, 0);
                    acc[ms][ns] = __builtin_amdgcn_mfma_f32_16x16x32_bf16(amh[ms], bnl[ns], acc[ms][ns], 0, 0, 0);
                    acc[ms][ns] = __builtin_amdgcn_mfma_f32_16x16x32_bf16(aml[ms], bnh[ns], acc[ms][ns], 0, 0, 0);
                }
        }
    }

    const float* bias = is_q ? b1 : b2;
    #pragma unroll
    for (int ns = 0; ns < 2; ++ns) {
        const int gn = n0 + wn + ns * 16 + (lane & 15);
        const float bv = bias[gn];
        #pragma unroll
        for (int ms = 0; ms < 2; ++ms) {
            #pragma unroll
            for (int r = 0; r < 4; ++r) {
                const int gm = mbase + wm + ms * 16 + (lane >> 4) * 4 + r;
                const float e = EXP2(fminf((acc[ms][ns][r] + bv) * PRESCALE, QCLAMP));
                if (is_q) {
                    abuf[(size_t)gm * 512 + gn] = e;
                } else {
                    const int srow = gm - 1024;
                    const int bb = srow >> 9, ss = srow & 511;
                    bT4[(((size_t)(bb * 128 + (gn >> 2)) * 512) + ss) * 4 + (gn & 3)] = e;
                }
            }
        }
    }
}

// ---------------------------------------------------------------------------
// 4-way rcp batching: sum V_i/x_i = [(V0x1+V1x0)p23 + (V2x3+V3x2)p01]/(p01 p23)
// ---------------------------------------------------------------------------
__device__ __forceinline__ float quad_term(float4 qa, float4 kb, float4 v4, float acc) {
    float x0 = fmaf(qa.x, kb.x, 1.f);
    float x1 = fmaf(qa.y, kb.y, 1.f);
    float x2 = fmaf(qa.z, kb.z, 1.f);
    float x3 = fmaf(qa.w, kb.w, 1.f);
    float p01 = x0 * x1, p23 = x2 * x3;
    float n01 = fmaf(v4.y, x0, v4.x * x1);
    float n23 = fmaf(v4.w, x2, v4.z * x3);
    float num = fmaf(n23, p01, n01 * p23);
    float den = p01 * p23;
    return fmaf(num, __builtin_amdgcn_rcpf(den), acc);
}

// ---------------------------------------------------------------------------
// K2: score -> e = exp(score) directly.  kb LDS-staged (per-lane ds_read);
// q read via wave-uniform SCALAR loads straight from abuf (s_load through the
// scalar cache — zero LDS/VMEM-pipe cost; the R18 version's 4 uniform q reads
// per iter went through the LDS pipe and made it the bottleneck).
// Inner loop per h4: 1 ds_read_b128 (12 cy) + 4 s_load_dwordx4 + ~144 cy VALU
// -> VALU-bound (per CU @ 8 waves: 96 cy LDS << 288 cy VALU wall).
// Block = (s-chunk 64, 16 t, b), 256 thr = 4 waves x 4 t-rows; lane = s.
// Grid (8,16,4) = 512 blocks; LDS 32 KB.
// ---------------------------------------------------------------------------
__global__ __launch_bounds__(256) void score_e(
    const float* __restrict__ abuf, const float* __restrict__ bT4,
    const float* __restrict__ Vp, const float* __restrict__ bVp,
    u16* __restrict__ e_hi, u16* __restrict__ e_lo, float* __restrict__ Zp)
{
    __shared__ float klds[32 * 64 * 4];   // 32 KB  [h4][s][4]

    const int tid  = threadIdx.x;
    const int lane = tid & 63;
    const int w    = tid >> 6;            // 0..3
    const int sc   = blockIdx.x;          // s-chunk 0..7
    const int t0   = blockIdx.y * 16;
    const int b    = blockIdx.z;
    const int s0   = sc * 64;

    // pv = sum(V) + bV (all lanes)
    float pv = 0.f;
    #pragma unroll
    for (int i = 0; i < 8; ++i) pv += Vp[i * 64 + lane];
    #pragma unroll
    for (int off = 32; off; off >>= 1) pv += __shfl_xor(pv, off);
    pv += bVp[0];

    // wave-uniform q-row bases -> scalar loads in the inner loop
    const int tr = t0 + w * 4;
    const float* a0 = abuf + __builtin_amdgcn_readfirstlane((b * T + tr + 0) * H);
    const float* a1 = abuf + __builtin_amdgcn_readfirstlane((b * T + tr + 1) * H);
    const float* a2 = abuf + __builtin_amdgcn_readfirstlane((b * T + tr + 2) * H);
    const float* a3 = abuf + __builtin_amdgcn_readfirstlane((b * T + tr + 3) * H);

    float acc0 = 0.f, acc1 = 0.f, acc2 = 0.f, acc3 = 0.f;

    for (int hc = 0; hc < 4; ++hc) {
        const int h0 = hc * 128;
        __syncthreads();   // previous chunk's reads complete before overwrite

        // stage kb chunk: 2048 float4 = [i=h4 0..31][si=s 0..63], flat copy
        const float4* kb_src = (const float4*)bT4 + (size_t)(b * 128 + (h0 >> 2)) * S + s0;
        #pragma unroll
        for (int j = 0; j < 8; ++j) {
            const int flat = tid + j * 256;       // 0..2047
            const int i  = flat >> 6;             // h4 row
            const int si = flat & 63;             // s
            ((float4*)klds)[flat] = kb_src[(size_t)i * S + si];
        }
        __syncthreads();

        #pragma unroll 8
        for (int i = 0; i < 32; ++i) {
            float4 kb = ((const float4*)klds)[i * 64 + lane];
            float4 v4 = *(const float4*)&Vp[h0 + i * 4];
            acc0 = quad_term(*(const float4*)&a0[h0 + i * 4], kb, v4, acc0);
            acc1 = quad_term(*(const float4*)&a1[h0 + i * 4], kb, v4, acc1);
            acc2 = quad_term(*(const float4*)&a2[h0 + i * 4], kb, v4, acc2);
            acc3 = quad_term(*(const float4*)&a3[h0 + i * 4], kb, v4, acc3);
        }
    }

    float e4[4];
    e4[0] = EXP2(fmaf(-2.f, acc0, pv) * LOG2E);
    e4[1] = EXP2(fmaf(-2.f, acc1, pv) * LOG2E);
    e4[2] = EXP2(fmaf(-2.f, acc2, pv) * LOG2E);
    e4[3] = EXP2(fmaf(-2.f, acc3, pv) * LOG2E);

    #pragma unroll
    for (int r = 0; r < 4; ++r) {
        float z = e4[r];
        #pragma unroll
        for (int off = 32; off; off >>= 1) z += __shfl_xor(z, off);

        unsigned u = __float_as_uint(e4[r]);
        unsigned hb = u & 0xFFFF0000u;
        const size_t row = (size_t)(b * T + tr + r);
        e_hi[row * S + s0 + lane] = (u16)(hb >> 16);
        e_lo[row * S + s0 + lane] = f2bf(e4[r] - __uint_as_float(hb));
        if (lane == 0) Zp[(size_t)sc * BT + row] = z;
    }
}

// ---------------------------------------------------------------------------
// K3: context GEMM via MFMA:  out[b][t][h] = (e @ enc)[t][h] / Z[t]
// 64x64 tile, 4 waves, BK=64 — clone of K1's staging/swizzle pattern.
// Grid (8 h-tiles, 4 m-tiles, 4 b) = 128 blocks.
// ---------------------------------------------------------------------------
__global__ __launch_bounds__(256) void ctx_mfma(
    const u16* __restrict__ e_hi, const u16* __restrict__ e_lo,
    const u16* __restrict__ eT_hi, const u16* __restrict__ eT_lo,
    const float* __restrict__ Zp, float* __restrict__ out)
{
    __shared__ u16 lds[4 * 4096];
    __shared__ float zinv[64];

    const int tid  = threadIdx.x;
    const int lane = tid & 63;
    const int w    = tid >> 6;
    const int n0   = blockIdx.x * 64;     // h
    const int m0   = blockIdx.y * 64;     // t within batch
    const int b    = blockIdx.z;

    if (tid < 64) {
        float z = 0.f;
        #pragma unroll
        for (int c = 0; c < 8; ++c) z += Zp[(size_t)c * BT + b * T + m0 + tid];
        zinv[tid] = __builtin_amdgcn_rcpf(z);
    }

    const int wm = (w & 1) * 32;
    const int wn = (w >> 1) * 32;
    const int r0  = tid >> 3;
    const int kc0 = tid & 7;

    const size_t abase = (size_t)(b * T + m0);
    const size_t bbase = (size_t)b * H + n0;

    f32x4 acc[2][2] = {};

    for (int kb = 0; kb < 8; ++kb) {
        const int k0 = kb * 64 + kc0 * 8;
        const size_t ga0 = (abase + r0) * S + k0;
        const size_t ga1 = (abase + r0 + 32) * S + k0;
        const size_t gw0 = (bbase + r0) * S + k0;
        const size_t gw1 = (bbase + r0 + 32) * S + k0;
        bf16x8 ah0 = *(const bf16x8*)&e_hi[ga0];
        bf16x8 ah1 = *(const bf16x8*)&e_hi[ga1];
        bf16x8 al0 = *(const bf16x8*)&e_lo[ga0];
        bf16x8 al1 = *(const bf16x8*)&e_lo[ga1];
        bf16x8 wh0 = *(const bf16x8*)&eT_hi[gw0];
        bf16x8 wh1 = *(const bf16x8*)&eT_hi[gw1];
        bf16x8 wl0 = *(const bf16x8*)&eT_lo[gw0];
        bf16x8 wl1 = *(const bf16x8*)&eT_lo[gw1];
        __syncthreads();
        const int sw  = (kc0 ^ (r0 & 7)) << 3;
        const int s0o = r0 * 64 + sw;
        const int s1o = (r0 + 32) * 64 + sw;
        *(bf16x8*)&lds[0 * 4096 + s0o] = ah0;  *(bf16x8*)&lds[0 * 4096 + s1o] = ah1;
        *(bf16x8*)&lds[1 * 4096 + s0o] = al0;  *(bf16x8*)&lds[1 * 4096 + s1o] = al1;
        *(bf16x8*)&lds[2 * 4096 + s0o] = wh0;  *(bf16x8*)&lds[2 * 4096 + s1o] = wh1;
        *(bf16x8*)&lds[3 * 4096 + s0o] = wl0;  *(bf16x8*)&lds[3 * 4096 + s1o] = wl1;
        __syncthreads();

        #pragma unroll
        for (int ks = 0; ks < 2; ++ks) {
            const int kg = ks * 4 + (lane >> 4);
            bf16x8 amh[2], aml[2], bnh[2], bnl[2];
            #pragma unroll
            for (int ms = 0; ms < 2; ++ms) {
                const int row = wm + ms * 16 + (lane & 15);
                const int off = row * 64 + ((kg ^ (row & 7)) << 3);
                amh[ms] = *(const bf16x8*)&lds[0 * 4096 + off];
                aml[ms] = *(const bf16x8*)&lds[1 * 4096 + off];
            }
            #pragma unroll
            for (int ns = 0; ns < 2; ++ns) {
                const int row = wn + ns * 16 + (lane & 15);
                const int off = row * 64 + ((kg ^ (row & 7)) << 3);
                bnh[ns] = *(const bf16x8*)&lds[2 * 4096 + off];
                bnl[ns] = *(const bf16x8*)&lds[3 * 4096 + off];
            }
            #pragma unroll
            for (int ms = 0; ms < 2; ++ms)
                #pragma unroll
                for (int ns = 0; ns < 2; ++ns) {
                    acc[ms][ns] = __builtin_amdgcn_mfma_f32_16x16x32_bf16(amh[ms], bnh[ns], acc[ms][ns], 0, 0, 0);
                    acc[ms][ns] = __builtin_amdgcn_mfma_f32_16x16x32_bf16(amh[ms], bnl[ns], acc[ms][ns], 0, 0, 0);
                    acc[ms][ns] = __builtin_amdgcn_mfma_f32_16x16x32_bf16(aml[ms], bnh[ns], acc[ms][ns], 0, 0, 0);
                }
        }
    }

    #pragma unroll
    for (int ns = 0; ns < 2; ++ns) {
        const int col = n0 + wn + ns * 16 + (lane & 15);
        #pragma unroll
        for (int ms = 0; ms < 2; ++ms) {
            #pragma unroll
            for (int r = 0; r < 4; ++r) {
                const int row = wm + ms * 16 + (lane >> 4) * 4 + r;
                out[((size_t)(b * T + m0 + row)) * H + col] = acc[ms][ns][r] * zinv[row];
            }
        }
    }
}

extern "C" void kernel_launch(void* const* d_in, const int* in_sizes, int n_in,
                              void* d_out, int out_size, void* d_ws, size_t ws_size,
                              hipStream_t stream) {
    const float* dh  = (const float*)d_in[0];
    const float* enc = (const float*)d_in[1];
    const float* W1  = (const float*)d_in[2];
    const float* b1  = (const float*)d_in[3];
    const float* W2  = (const float*)d_in[4];
    const float* b2  = (const float*)d_in[5];
    const float* V   = (const float*)d_in[6];
    const float* bV  = (const float*)d_in[7];

    float* abuf   = (float*)d_ws;                       // B*T*H f32 = 2 MB
    float* bT4    = abuf + (size_t)B * T * H;           // B*S*H f32 = 4 MB
    u16*  encT_hi = (u16*)(bT4 + (size_t)B * S * H);    // B*H*S u16 = 2 MB
    u16*  encT_lo = encT_hi + (size_t)B * H * S;        // 2 MB
    u16*  e_hi    = encT_lo + (size_t)B * H * S;        // B*T*S u16 = 1 MB
    u16*  e_lo    = e_hi + (size_t)B * T * S;           // 1 MB
    float* Zp     = (float*)(e_lo + (size_t)B * T * S); // 8*BT f32 = 32 KB

    mfma_proj<<<dim3(8, 80),    dim3(256), 0, stream>>>(dh, enc, W1, W2, b1, b2,
                                                        abuf, bT4, encT_hi, encT_lo);
    score_e  <<<dim3(8, 16, 4), dim3(256), 0, stream>>>(abuf, bT4, V, bV, e_hi, e_lo, Zp);
    ctx_mfma <<<dim3(8, 4, 4),  dim3(256), 0, stream>>>(e_hi, e_lo, encT_hi, encT_lo,
                                                        Zp, (float*)d_out);
}

// Round 20
// 58.637 us; speedup vs baseline: 1.2026x; 1.2026x over previous
//
#include <hip/hip_runtime.h>

#define B 4
#define T 256
#define S 512
#define H 512
#define BT (B*T)          // 1024

// 2 * log2(e): projections are prescaled so exp2 replaces exp in tanh.
#define PRESCALE 2.8853900817779268f
#define LOG2E 1.4426950408889634f
#define QCLAMP 15.0f      // clamp exp2 arg: ab <= 2^30, den (4-way) <= 2^122

typedef unsigned short u16;
typedef __attribute__((ext_vector_type(8))) short bf16x8;   // 8 bf16 in 4 VGPRs
typedef __attribute__((ext_vector_type(4))) float f32x4;

#if __has_builtin(__builtin_amdgcn_exp2f)
#define EXP2(x) __builtin_amdgcn_exp2f(x)
#else
#define EXP2(x) exp2f(x)
#endif

__device__ __forceinline__ u16 f2bf(float x) {              // RNE fp32->bf16
    unsigned u = __float_as_uint(x);
    u = u + 0x7FFFu + ((u >> 16) & 1u);
    return (u16)(u >> 16);
}

// split 8 fp32 -> bf16 hi (truncated) + bf16 lo (RNE of residual).
__device__ __forceinline__ void split8(float4 f0, float4 f1, bf16x8& hi, bf16x8& lo) {
    float x[8] = {f0.x, f0.y, f0.z, f0.w, f1.x, f1.y, f1.z, f1.w};
    #pragma unroll
    for (int i = 0; i < 8; ++i) {
        unsigned u = __float_as_uint(x[i]);
        unsigned h = u & 0xFFFF0000u;
        hi[i] = (short)(h >> 16);
        lo[i] = (short)f2bf(x[i] - __uint_as_float(h));
    }
}

// ---------------------------------------------------------------------------
// K1: MFMA projection GEMM (fused fp32->bf16 hi/lo split, exp2 epilogue).
//   blockIdx.y <  48: projection tiles (q rows -> abuf; k rows -> bT4)
//   blockIdx.y >= 48: enc transpose+split tiles -> encT_hi/lo[b][h][s]
// bT4 layout is s-chunk-major: [b][sc][h4][64 s][4] so score_e's wave
// streams a contiguous 128 KB region (sequential 1 KB steps).
// ---------------------------------------------------------------------------
__global__ __launch_bounds__(256) void mfma_proj(
    const float* __restrict__ dh, const float* __restrict__ enc,
    const float* __restrict__ W1, const float* __restrict__ W2,
    const float* __restrict__ b1, const float* __restrict__ b2,
    float* __restrict__ abuf, float* __restrict__ bT4,
    u16* __restrict__ encT_hi, u16* __restrict__ encT_lo)
{
    __shared__ u16 lds[4 * 4096];   // 32 KB; transpose path reuses as f32[64][65]

    const int tid   = threadIdx.x;
    const int n0    = blockIdx.x * 64;
    const int mTile = blockIdx.y;           // 0..79

    if (mTile >= 48) {
        // ---- enc transpose + split:  enc[b][s][h] -> encT[b][h][s] ----
        float (*TTf)[65] = reinterpret_cast<float(*)[65]>(lds);
        const int ty = mTile - 48;   // 0..31
        const int bb = ty >> 3;      // batch
        const int st = ty & 7;       // s-tile
        const int c64 = tid & 63;
        const int r4  = tid >> 6;
        #pragma unroll
        for (int rr = 0; rr < 16; ++rr) {
            const int r = rr * 4 + r4;
            TTf[r][c64] = enc[((size_t)(bb * S + st * 64 + r)) * H + n0 + c64];
        }
        __syncthreads();
        const int hr = tid >> 2;           // 0..63 (h within tile)
        const int sq = (tid & 3) * 16;     // 16 s per thread
        u16* ehp = encT_hi + ((size_t)(bb * H + n0 + hr)) * S + st * 64 + sq;
        u16* elp = encT_lo + ((size_t)(bb * H + n0 + hr)) * S + st * 64 + sq;
        #pragma unroll
        for (int j4 = 0; j4 < 4; ++j4) {
            ushort4 hv, lv;
            #pragma unroll
            for (int jj = 0; jj < 4; ++jj) {
                float x = TTf[sq + j4 * 4 + jj][hr];
                unsigned u = __float_as_uint(x);
                unsigned hb = u & 0xFFFF0000u;
                u16 hh = (u16)(hb >> 16);
                u16 ll = f2bf(x - __uint_as_float(hb));
                if (jj == 0) { hv.x = hh; lv.x = ll; }
                else if (jj == 1) { hv.y = hh; lv.y = ll; }
                else if (jj == 2) { hv.z = hh; lv.z = ll; }
                else { hv.w = hh; lv.w = ll; }
            }
            *(ushort4*)&ehp[j4 * 4] = hv;
            *(ushort4*)&elp[j4 * 4] = lv;
        }
        return;
    }

    const int lane  = tid & 63;
    const int w     = tid >> 6;
    const int mbase = mTile * 64;
    const bool is_q = (mTile < 16);

    const float* Asrc = is_q ? dh : enc;
    const float* Wsrc = is_q ? W1 : W2;
    const int arow = is_q ? mbase : (mbase - 1024);

    const int wm = (w & 1) * 32;
    const int wn = (w >> 1) * 32;

    const int r0  = tid >> 3;               // staging row 0..31 (second: +32)
    const int kc0 = tid & 7;                // staging k-chunk

    f32x4 acc[2][2] = {};                   // [ms][ns]

    for (int kb = 0; kb < 8; ++kb) {
        const int k0 = kb * 64 + kc0 * 8;
        const size_t ga0 = (size_t)(arow + r0) * 512 + k0;
        const size_t ga1 = (size_t)(arow + r0 + 32) * 512 + k0;
        const size_t gw0 = (size_t)(n0 + r0) * 512 + k0;
        const size_t gw1 = (size_t)(n0 + r0 + 32) * 512 + k0;
        bf16x8 ah0, al0, ah1, al1, wh0, wl0, wh1, wl1;
        split8(*(const float4*)&Asrc[ga0], *(const float4*)&Asrc[ga0 + 4], ah0, al0);
        split8(*(const float4*)&Asrc[ga1], *(const float4*)&Asrc[ga1 + 4], ah1, al1);
        split8(*(const float4*)&Wsrc[gw0], *(const float4*)&Wsrc[gw0 + 4], wh0, wl0);
        split8(*(const float4*)&Wsrc[gw1], *(const float4*)&Wsrc[gw1 + 4], wh1, wl1);
        __syncthreads();
        const int sw  = (kc0 ^ (r0 & 7)) << 3;       // (r0+32)&7 == r0&7
        const int s0o = r0 * 64 + sw;
        const int s1o = (r0 + 32) * 64 + sw;
        *(bf16x8*)&lds[0 * 4096 + s0o] = ah0;  *(bf16x8*)&lds[0 * 4096 + s1o] = ah1;
        *(bf16x8*)&lds[1 * 4096 + s0o] = al0;  *(bf16x8*)&lds[1 * 4096 + s1o] = al1;
        *(bf16x8*)&lds[2 * 4096 + s0o] = wh0;  *(bf16x8*)&lds[2 * 4096 + s1o] = wh1;
        *(bf16x8*)&lds[3 * 4096 + s0o] = wl0;  *(bf16x8*)&lds[3 * 4096 + s1o] = wl1;
        __syncthreads();

        #pragma unroll
        for (int ks = 0; ks < 2; ++ks) {
            const int kg = ks * 4 + (lane >> 4);     // k-chunk 0..7
            bf16x8 amh[2], aml[2], bnh[2], bnl[2];
            #pragma unroll
            for (int ms = 0; ms < 2; ++ms) {
                const int row = wm + ms * 16 + (lane & 15);
                const int off = row * 64 + ((kg ^ (row & 7)) << 3);
                amh[ms] = *(const bf16x8*)&lds[0 * 4096 + off];
                aml[ms] = *(const bf16x8*)&lds[1 * 4096 + off];
            }
            #pragma unroll
            for (int ns = 0; ns < 2; ++ns) {
                const int row = wn + ns * 16 + (lane & 15);
                const int off = row * 64 + ((kg ^ (row & 7)) << 3);
                bnh[ns] = *(const bf16x8*)&lds[2 * 4096 + off];
                bnl[ns] = *(const bf16x8*)&lds[3 * 4096 + off];
            }
            #pragma unroll
            for (int ms = 0; ms < 2; ++ms)
                #pragma unroll
                for (int ns = 0; ns < 2; ++ns) {
                    acc[ms][ns] = __builtin_amdgcn_mfma_f32_16x16x32_bf16(amh[ms], bnh[ns], acc[ms][ns], 0, 0, 0);
                    acc[ms][ns] = __builtin_amdgcn_mfma_f32_16x16x32_bf16(amh[ms], bnl[ns], acc[ms][ns], 0, 0, 0);
                    acc[ms][ns] = __builtin_amdgcn_mfma_f32_16x16x32_bf16(aml[ms], bnh[ns], acc[ms][ns], 0, 0, 0);
                }
        }
    }

    const float* bias = is_q ? b1 : b2;
    #pragma unroll
    for (int ns = 0; ns < 2; ++ns) {
        const int gn = n0 + wn + ns * 16 + (lane & 15);
        const float bv = bias[gn];
        #pragma unroll
        for (int ms = 0; ms < 2; ++ms) {
            #pragma unroll
            for (int r = 0; r < 4; ++r) {
                const int gm = mbase + wm + ms * 16 + (lane >> 4) * 4 + r;
                const float e = EXP2(fminf((acc[ms][ns][r] + bv) * PRESCALE, QCLAMP));
                if (is_q) {
                    abuf[(size_t)gm * 512 + gn] = e;
                } else {
                    const int srow = gm - 1024;
                    const int bb = srow >> 9, ss = srow & 511;
                    const int sc = ss >> 6, sl = ss & 63;
                    // [b][sc][h4][64 s][4]
                    bT4[((((size_t)(bb * 8 + sc) * 128) + (gn >> 2)) * 64 + sl) * 4 + (gn & 3)] = e;
                }
            }
        }
    }
}

// ---------------------------------------------------------------------------
// 4-way rcp batching: sum V_i/x_i = [(V0x1+V1x0)p23 + (V2x3+V3x2)p01]/(p01 p23)
// ---------------------------------------------------------------------------
__device__ __forceinline__ float quad_term(float4 qa, float4 kb, float4 v4, float acc) {
    float x0 = fmaf(qa.x, kb.x, 1.f);
    float x1 = fmaf(qa.y, kb.y, 1.f);
    float x2 = fmaf(qa.z, kb.z, 1.f);
    float x3 = fmaf(qa.w, kb.w, 1.f);
    float p01 = x0 * x1, p23 = x2 * x3;
    float n01 = fmaf(v4.y, x0, v4.x * x1);
    float n23 = fmaf(v4.w, x2, v4.z * x3);
    float num = fmaf(n23, p01, n01 * p23);
    float den = p01 * p23;
    return fmaf(num, __builtin_amdgcn_rcpf(den), acc);
}

// ---------------------------------------------------------------------------
// K2: score -> e = exp(score) directly (no max subtraction: |score| <= ~11.5
// deterministically).  Writes e as bf16 hi/lo + per-(s-chunk,row) sums Zp.
// Block = (s-chunk 64, 16 t, b), 512 thr = 8 waves x 2 t-rows; lane = s.
// Grid (8,16,4) = 512 blocks.  With the s-chunk-major bT4 layout, each
// wave's kb stream is a contiguous 128 KB region read in sequential 1 KB
// steps (prefetch/TLB-friendly), vs 8 KB-stride jumps before.
// ---------------------------------------------------------------------------
__global__ __launch_bounds__(512) void score_e(
    const float* __restrict__ abuf, const float* __restrict__ bT4,
    const float* __restrict__ Vp, const float* __restrict__ bVp,
    u16* __restrict__ e_hi, u16* __restrict__ e_lo, float* __restrict__ Zp)
{
    const int tid  = threadIdx.x;
    const int lane = tid & 63;
    const int w    = tid >> 6;            // 0..7
    const int sc   = blockIdx.x;          // s-chunk 0..7
    const int t0   = blockIdx.y * 16;
    const int b    = blockIdx.z;
    const int s0   = sc * 64;

    // pv = sum(V) + bV (all lanes)
    float pv = 0.f;
    #pragma unroll
    for (int i = 0; i < 8; ++i) pv += Vp[i * 64 + lane];
    #pragma unroll
    for (int off = 32; off; off >>= 1) pv += __shfl_xor(pv, off);
    pv += bVp[0];

    const int ta = t0 + w * 2;
    const int tb = ta + 1;
    const float* aA = abuf + __builtin_amdgcn_readfirstlane((b * T + ta) * H);
    const float* aB = abuf + __builtin_amdgcn_readfirstlane((b * T + tb) * H);
    // contiguous kb region for this (b, sc): 128 h4-steps of 64 float4
    const float4* bp = (const float4*)bT4 + ((size_t)(b * 8 + sc) * 128) * 64 + lane;

    float accA = 0.f, accB = 0.f;
    #pragma unroll 4
    for (int h4 = 0; h4 < 128; ++h4) {
        float4 kb = bp[h4 * 64];
        float4 v4 = *(const float4*)&Vp[h4 * 4];
        float4 qA = *(const float4*)&aA[h4 * 4];
        float4 qB = *(const float4*)&aB[h4 * 4];
        accA = quad_term(qA, kb, v4, accA);
        accB = quad_term(qB, kb, v4, accB);
    }
    const float xA = fmaf(-2.f, accA, pv);
    const float xB = fmaf(-2.f, accB, pv);

    const float eA = EXP2(xA * LOG2E);
    const float eB = EXP2(xB * LOG2E);

    float zA = eA, zB = eB;
    #pragma unroll
    for (int off = 32; off; off >>= 1) {
        zA += __shfl_xor(zA, off);
        zB += __shfl_xor(zB, off);
    }

    // split e -> bf16 hi/lo, coalesced u16 stores
    unsigned uA = __float_as_uint(eA), uB = __float_as_uint(eB);
    unsigned hA = uA & 0xFFFF0000u,   hB = uB & 0xFFFF0000u;
    const size_t rowA = (size_t)(b * T + ta);
    const size_t rowB = (size_t)(b * T + tb);
    e_hi[rowA * S + s0 + lane] = (u16)(hA >> 16);
    e_lo[rowA * S + s0 + lane] = f2bf(eA - __uint_as_float(hA));
    e_hi[rowB * S + s0 + lane] = (u16)(hB >> 16);
    e_lo[rowB * S + s0 + lane] = f2bf(eB - __uint_as_float(hB));

    if (lane == 0) {
        Zp[(size_t)sc * BT + rowA] = zA;
        Zp[(size_t)sc * BT + rowB] = zB;
    }
}

// ---------------------------------------------------------------------------
// K3: context GEMM via MFMA:  out[b][t][h] = (e @ enc)[t][h] / Z[t]
// 64x64 tile, 4 waves, BK=64 — clone of K1's staging/swizzle pattern.
// Grid (8 h-tiles, 4 m-tiles, 4 b) = 128 blocks.
// ---------------------------------------------------------------------------
__global__ __launch_bounds__(256) void ctx_mfma(
    const u16* __restrict__ e_hi, const u16* __restrict__ e_lo,
    const u16* __restrict__ eT_hi, const u16* __restrict__ eT_lo,
    const float* __restrict__ Zp, float* __restrict__ out)
{
    __shared__ u16 lds[4 * 4096];
    __shared__ float zinv[64];

    const int tid  = threadIdx.x;
    const int lane = tid & 63;
    const int w    = tid >> 6;
    const int n0   = blockIdx.x * 64;     // h
    const int m0   = blockIdx.y * 64;     // t within batch
    const int b    = blockIdx.z;

    if (tid < 64) {
        float z = 0.f;
        #pragma unroll
        for (int c = 0; c < 8; ++c) z += Zp[(size_t)c * BT + b * T + m0 + tid];
        zinv[tid] = __builtin_amdgcn_rcpf(z);
    }

    const int wm = (w & 1) * 32;
    const int wn = (w >> 1) * 32;
    const int r0  = tid >> 3;
    const int kc0 = tid & 7;

    const size_t abase = (size_t)(b * T + m0);
    const size_t bbase = (size_t)b * H + n0;

    f32x4 acc[2][2] = {};

    for (int kb = 0; kb < 8; ++kb) {
        const int k0 = kb * 64 + kc0 * 8;
        const size_t ga0 = (abase + r0) * S + k0;
        const size_t ga1 = (abase + r0 + 32) * S + k0;
        const size_t gw0 = (bbase + r0) * S + k0;
        const size_t gw1 = (bbase + r0 + 32) * S + k0;
        bf16x8 ah0 = *(const bf16x8*)&e_hi[ga0];
        bf16x8 ah1 = *(const bf16x8*)&e_hi[ga1];
        bf16x8 al0 = *(const bf16x8*)&e_lo[ga0];
        bf16x8 al1 = *(const bf16x8*)&e_lo[ga1];
        bf16x8 wh0 = *(const bf16x8*)&eT_hi[gw0];
        bf16x8 wh1 = *(const bf16x8*)&eT_hi[gw1];
        bf16x8 wl0 = *(const bf16x8*)&eT_lo[gw0];
        bf16x8 wl1 = *(const bf16x8*)&eT_lo[gw1];
        __syncthreads();
        const int sw  = (kc0 ^ (r0 & 7)) << 3;
        const int s0o = r0 * 64 + sw;
        const int s1o = (r0 + 32) * 64 + sw;
        *(bf16x8*)&lds[0 * 4096 + s0o] = ah0;  *(bf16x8*)&lds[0 * 4096 + s1o] = ah1;
        *(bf16x8*)&lds[1 * 4096 + s0o] = al0;  *(bf16x8*)&lds[1 * 4096 + s1o] = al1;
        *(bf16x8*)&lds[2 * 4096 + s0o] = wh0;  *(bf16x8*)&lds[2 * 4096 + s1o] = wh1;
        *(bf16x8*)&lds[3 * 4096 + s0o] = wl0;  *(bf16x8*)&lds[3 * 4096 + s1o] = wl1;
        __syncthreads();

        #pragma unroll
        for (int ks = 0; ks < 2; ++ks) {
            const int kg = ks * 4 + (lane >> 4);
            bf16x8 amh[2], aml[2], bnh[2], bnl[2];
            #pragma unroll
            for (int ms = 0; ms < 2; ++ms) {
                const int row = wm + ms * 16 + (lane & 15);
                const int off = row * 64 + ((kg ^ (row & 7)) << 3);
                amh[ms] = *(const bf16x8*)&lds[0 * 4096 + off];
                aml[ms] = *(const bf16x8*)&lds[1 * 4096 + off];
            }
            #pragma unroll
            for (int ns = 0; ns < 2; ++ns) {
                const int row = wn + ns * 16 + (lane & 15);
                const int off = row * 64 + ((kg ^ (row & 7)) << 3);
                bnh[ns] = *(const bf16x8*)&lds[2 * 4096 + off];
                bnl[ns] = *(const bf16x8*)&lds[3 * 4096 + off];
            }
            #pragma unroll
            for (int ms = 0; ms < 2; ++ms)
                #pragma unroll
                for (int ns = 0; ns < 2; ++ns) {
                    acc[ms][ns] = __builtin_amdgcn_mfma_f32_16x16x32_bf16(amh[ms], bnh[ns], acc[ms][ns], 0, 0, 0);
                    acc[ms][ns] = __builtin_amdgcn_mfma_f32_16x16x32_bf16(amh[ms], bnl[ns], acc[ms][ns], 0, 0, 0);
                    acc[ms][ns] = __builtin_amdgcn_mfma_f32_16x16x32_bf16(aml[ms], bnh[ns], acc[ms][ns], 0, 0, 0);
                }
        }
    }

    #pragma unroll
    for (int ns = 0; ns < 2; ++ns) {
        const int col = n0 + wn + ns * 16 + (lane & 15);
        #pragma unroll
        for (int ms = 0; ms < 2; ++ms) {
            #pragma unroll
            for (int r = 0; r < 4; ++r) {
                const int row = wm + ms * 16 + (lane >> 4) * 4 + r;
                out[((size_t)(b * T + m0 + row)) * H + col] = acc[ms][ns][r] * zinv[row];
            }
        }
    }
}

extern "C" void kernel_launch(void* const* d_in, const int* in_sizes, int n_in,
                              void* d_out, int out_size, void* d_ws, size_t ws_size,
                              hipStream_t stream) {
    const float* dh  = (const float*)d_in[0];
    const float* enc = (const float*)d_in[1];
    const float* W1  = (const float*)d_in[2];
    const float* b1  = (const float*)d_in[3];
    const float* W2  = (const float*)d_in[4];
    const float* b2  = (const float*)d_in[5];
    const float* V   = (const float*)d_in[6];
    const float* bV  = (const float*)d_in[7];

    float* abuf   = (float*)d_ws;                       // B*T*H f32 = 2 MB
    float* bT4    = abuf + (size_t)B * T * H;           // B*S*H f32 = 4 MB
    u16*  encT_hi = (u16*)(bT4 + (size_t)B * S * H);    // B*H*S u16 = 2 MB
    u16*  encT_lo = encT_hi + (size_t)B * H * S;        // 2 MB
    u16*  e_hi    = encT_lo + (size_t)B * H * S;        // B*T*S u16 = 1 MB
    u16*  e_lo    = e_hi + (size_t)B * T * S;           // 1 MB
    float* Zp     = (float*)(e_lo + (size_t)B * T * S); // 8*BT f32 = 32 KB

    mfma_proj<<<dim3(8, 80),    dim3(256), 0, stream>>>(dh, enc, W1, W2, b1, b2,
                                                        abuf, bT4, encT_hi, encT_lo);
    score_e  <<<dim3(8, 16, 4), dim3(512), 0, stream>>>(abuf, bT4, V, bV, e_hi, e_lo, Zp);
    ctx_mfma <<<dim3(8, 4, 4),  dim3(256), 0, stream>>>(e_hi, e_lo, encT_hi, encT_lo,
                                                        Zp, (float*)d_out);
}

// Round 21
// 58.526 us; speedup vs baseline: 1.2049x; 1.0019x over previous
//
#include <hip/hip_runtime.h>

#define B 4
#define T 256
#define S 512
#define H 512
#define BT (B*T)          // 1024

// 2 * log2(e): projections are prescaled so exp2 replaces exp in tanh.
#define PRESCALE 2.8853900817779268f
#define LOG2E 1.4426950408889634f
#define QCLAMP 15.0f      // clamp exp2 arg: ab <= 2^30, den (4-way) <= 2^122

typedef unsigned short u16;
typedef __attribute__((ext_vector_type(8))) short bf16x8;   // 8 bf16 in 4 VGPRs
typedef __attribute__((ext_vector_type(4))) float f32x4;

#if __has_builtin(__builtin_amdgcn_exp2f)
#define EXP2(x) __builtin_amdgcn_exp2f(x)
#else
#define EXP2(x) exp2f(x)
#endif

__device__ __forceinline__ u16 f2bf(float x) {              // RNE fp32->bf16
    unsigned u = __float_as_uint(x);
    u = u + 0x7FFFu + ((u >> 16) & 1u);
    return (u16)(u >> 16);
}

// split 8 fp32 -> bf16 hi (truncated) + bf16 lo (RNE of residual).
__device__ __forceinline__ void split8(float4 f0, float4 f1, bf16x8& hi, bf16x8& lo) {
    float x[8] = {f0.x, f0.y, f0.z, f0.w, f1.x, f1.y, f1.z, f1.w};
    #pragma unroll
    for (int i = 0; i < 8; ++i) {
        unsigned u = __float_as_uint(x[i]);
        unsigned h = u & 0xFFFF0000u;
        hi[i] = (short)(h >> 16);
        lo[i] = (short)f2bf(x[i] - __uint_as_float(h));
    }
}

// ---------------------------------------------------------------------------
// K1: MFMA projection GEMM (fused fp32->bf16 hi/lo split, exp2 epilogue).
//   blockIdx.y <  48: projection tiles (q rows -> abuf; k rows -> bT4)
//   blockIdx.y >= 48: enc transpose+split tiles -> encT_hi/lo[b][h][s]
// bT4 layout is s-chunk-major: [b][sc][h4][64 s][4] so score_e's wave
// streams a contiguous 128 KB region (sequential 1 KB steps).
// ---------------------------------------------------------------------------
__global__ __launch_bounds__(256) void mfma_proj(
    const float* __restrict__ dh, const float* __restrict__ enc,
    const float* __restrict__ W1, const float* __restrict__ W2,
    const float* __restrict__ b1, const float* __restrict__ b2,
    float* __restrict__ abuf, float* __restrict__ bT4,
    u16* __restrict__ encT_hi, u16* __restrict__ encT_lo)
{
    __shared__ u16 lds[4 * 4096];   // 32 KB; transpose path reuses as f32[64][65]

    const int tid   = threadIdx.x;
    const int n0    = blockIdx.x * 64;
    const int mTile = blockIdx.y;           // 0..79

    if (mTile >= 48) {
        // ---- enc transpose + split:  enc[b][s][h] -> encT[b][h][s] ----
        float (*TTf)[65] = reinterpret_cast<float(*)[65]>(lds);
        const int ty = mTile - 48;   // 0..31
        const int bb = ty >> 3;      // batch
        const int st = ty & 7;       // s-tile
        const int c64 = tid & 63;
        const int r4  = tid >> 6;
        #pragma unroll
        for (int rr = 0; rr < 16; ++rr) {
            const int r = rr * 4 + r4;
            TTf[r][c64] = enc[((size_t)(bb * S + st * 64 + r)) * H + n0 + c64];
        }
        __syncthreads();
        const int hr = tid >> 2;           // 0..63 (h within tile)
        const int sq = (tid & 3) * 16;     // 16 s per thread
        u16* ehp = encT_hi + ((size_t)(bb * H + n0 + hr)) * S + st * 64 + sq;
        u16* elp = encT_lo + ((size_t)(bb * H + n0 + hr)) * S + st * 64 + sq;
        #pragma unroll
        for (int j4 = 0; j4 < 4; ++j4) {
            ushort4 hv, lv;
            #pragma unroll
            for (int jj = 0; jj < 4; ++jj) {
                float x = TTf[sq + j4 * 4 + jj][hr];
                unsigned u = __float_as_uint(x);
                unsigned hb = u & 0xFFFF0000u;
                u16 hh = (u16)(hb >> 16);
                u16 ll = f2bf(x - __uint_as_float(hb));
                if (jj == 0) { hv.x = hh; lv.x = ll; }
                else if (jj == 1) { hv.y = hh; lv.y = ll; }
                else if (jj == 2) { hv.z = hh; lv.z = ll; }
                else { hv.w = hh; lv.w = ll; }
            }
            *(ushort4*)&ehp[j4 * 4] = hv;
            *(ushort4*)&elp[j4 * 4] = lv;
        }
        return;
    }

    const int lane  = tid & 63;
    const int w     = tid >> 6;
    const int mbase = mTile * 64;
    const bool is_q = (mTile < 16);

    const float* Asrc = is_q ? dh : enc;
    const float* Wsrc = is_q ? W1 : W2;
    const int arow = is_q ? mbase : (mbase - 1024);

    const int wm = (w & 1) * 32;
    const int wn = (w >> 1) * 32;

    const int r0  = tid >> 3;               // staging row 0..31 (second: +32)
    const int kc0 = tid & 7;                // staging k-chunk

    f32x4 acc[2][2] = {};                   // [ms][ns]

    for (int kb = 0; kb < 8; ++kb) {
        const int k0 = kb * 64 + kc0 * 8;
        const size_t ga0 = (size_t)(arow + r0) * 512 + k0;
        const size_t ga1 = (size_t)(arow + r0 + 32) * 512 + k0;
        const size_t gw0 = (size_t)(n0 + r0) * 512 + k0;
        const size_t gw1 = (size_t)(n0 + r0 + 32) * 512 + k0;
        bf16x8 ah0, al0, ah1, al1, wh0, wl0, wh1, wl1;
        split8(*(const float4*)&Asrc[ga0], *(const float4*)&Asrc[ga0 + 4], ah0, al0);
        split8(*(const float4*)&Asrc[ga1], *(const float4*)&Asrc[ga1 + 4], ah1, al1);
        split8(*(const float4*)&Wsrc[gw0], *(const float4*)&Wsrc[gw0 + 4], wh0, wl0);
        split8(*(const float4*)&Wsrc[gw1], *(const float4*)&Wsrc[gw1 + 4], wh1, wl1);
        __syncthreads();
        const int sw  = (kc0 ^ (r0 & 7)) << 3;       // (r0+32)&7 == r0&7
        const int s0o = r0 * 64 + sw;
        const int s1o = (r0 + 32) * 64 + sw;
        *(bf16x8*)&lds[0 * 4096 + s0o] = ah0;  *(bf16x8*)&lds[0 * 4096 + s1o] = ah1;
        *(bf16x8*)&lds[1 * 4096 + s0o] = al0;  *(bf16x8*)&lds[1 * 4096 + s1o] = al1;
        *(bf16x8*)&lds[2 * 4096 + s0o] = wh0;  *(bf16x8*)&lds[2 * 4096 + s1o] = wh1;
        *(bf16x8*)&lds[3 * 4096 + s0o] = wl0;  *(bf16x8*)&lds[3 * 4096 + s1o] = wl1;
        __syncthreads();

        #pragma unroll
        for (int ks = 0; ks < 2; ++ks) {
            const int kg = ks * 4 + (lane >> 4);     // k-chunk 0..7
            bf16x8 amh[2], aml[2], bnh[2], bnl[2];
            #pragma unroll
            for (int ms = 0; ms < 2; ++ms) {
                const int row = wm + ms * 16 + (lane & 15);
                const int off = row * 64 + ((kg ^ (row & 7)) << 3);
                amh[ms] = *(const bf16x8*)&lds[0 * 4096 + off];
                aml[ms] = *(const bf16x8*)&lds[1 * 4096 + off];
            }
            #pragma unroll
            for (int ns = 0; ns < 2; ++ns) {
                const int row = wn + ns * 16 + (lane & 15);
                const int off = row * 64 + ((kg ^ (row & 7)) << 3);
                bnh[ns] = *(const bf16x8*)&lds[2 * 4096 + off];
                bnl[ns] = *(const bf16x8*)&lds[3 * 4096 + off];
            }
            #pragma unroll
            for (int ms = 0; ms < 2; ++ms)
                #pragma unroll
                for (int ns = 0; ns < 2; ++ns) {
                    acc[ms][ns] = __builtin_amdgcn_mfma_f32_16x16x32_bf16(amh[ms], bnh[ns], acc[ms][ns], 0, 0, 0);
                    acc[ms][ns] = __builtin_amdgcn_mfma_f32_16x16x32_bf16(amh[ms], bnl[ns], acc[ms][ns], 0, 0, 0);
                    acc[ms][ns] = __builtin_amdgcn_mfma_f32_16x16x32_bf16(aml[ms], bnh[ns], acc[ms][ns], 0, 0, 0);
                }
        }
    }

    const float* bias = is_q ? b1 : b2;
    #pragma unroll
    for (int ns = 0; ns < 2; ++ns) {
        const int gn = n0 + wn + ns * 16 + (lane & 15);
        const float bv = bias[gn];
        #pragma unroll
        for (int ms = 0; ms < 2; ++ms) {
            #pragma unroll
            for (int r = 0; r < 4; ++r) {
                const int gm = mbase + wm + ms * 16 + (lane >> 4) * 4 + r;
                const float e = EXP2(fminf((acc[ms][ns][r] + bv) * PRESCALE, QCLAMP));
                if (is_q) {
                    abuf[(size_t)gm * 512 + gn] = e;
                } else {
                    const int srow = gm - 1024;
                    const int bb = srow >> 9, ss = srow & 511;
                    const int sc = ss >> 6, sl = ss & 63;
                    // [b][sc][h4][64 s][4]
                    bT4[((((size_t)(bb * 8 + sc) * 128) + (gn >> 2)) * 64 + sl) * 4 + (gn & 3)] = e;
                }
            }
        }
    }
}

// ---------------------------------------------------------------------------
// 4-way rcp batching: sum V_i/x_i = [(V0x1+V1x0)p23 + (V2x3+V3x2)p01]/(p01 p23)
// ---------------------------------------------------------------------------
__device__ __forceinline__ float quad_term(float4 qa, float4 kb, float4 v4, float acc) {
    float x0 = fmaf(qa.x, kb.x, 1.f);
    float x1 = fmaf(qa.y, kb.y, 1.f);
    float x2 = fmaf(qa.z, kb.z, 1.f);
    float x3 = fmaf(qa.w, kb.w, 1.f);
    float p01 = x0 * x1, p23 = x2 * x3;
    float n01 = fmaf(v4.y, x0, v4.x * x1);
    float n23 = fmaf(v4.w, x2, v4.z * x3);
    float num = fmaf(n23, p01, n01 * p23);
    float den = p01 * p23;
    return fmaf(num, __builtin_amdgcn_rcpf(den), acc);
}

// ---------------------------------------------------------------------------
// K2: score -> e = exp(score) directly (no max subtraction: |score| <= ~11.5
// deterministically).  Writes e as bf16 hi/lo + per-(s-chunk,row) sums Zp.
// Block = (s-chunk 64, 16 t, b), 512 thr = 8 waves x 2 t-rows; lane = s.
// Grid (8,16,4) = 512 blocks.  s-chunk-major bT4: contiguous 128 KB kb
// stream per wave.  Unroll 8: ~8 KB of kb loads in flight per wave so the
// ~250 cy L2 latency is covered by ~480 cy of VALU per unroll group.
// ---------------------------------------------------------------------------
__global__ __launch_bounds__(512) void score_e(
    const float* __restrict__ abuf, const float* __restrict__ bT4,
    const float* __restrict__ Vp, const float* __restrict__ bVp,
    u16* __restrict__ e_hi, u16* __restrict__ e_lo, float* __restrict__ Zp)
{
    const int tid  = threadIdx.x;
    const int lane = tid & 63;
    const int w    = tid >> 6;            // 0..7
    const int sc   = blockIdx.x;          // s-chunk 0..7
    const int t0   = blockIdx.y * 16;
    const int b    = blockIdx.z;
    const int s0   = sc * 64;

    // pv = sum(V) + bV (all lanes)
    float pv = 0.f;
    #pragma unroll
    for (int i = 0; i < 8; ++i) pv += Vp[i * 64 + lane];
    #pragma unroll
    for (int off = 32; off; off >>= 1) pv += __shfl_xor(pv, off);
    pv += bVp[0];

    const int ta = t0 + w * 2;
    const int tb = ta + 1;
    const float* aA = abuf + __builtin_amdgcn_readfirstlane((b * T + ta) * H);
    const float* aB = abuf + __builtin_amdgcn_readfirstlane((b * T + tb) * H);
    // contiguous kb region for this (b, sc): 128 h4-steps of 64 float4
    const float4* bp = (const float4*)bT4 + ((size_t)(b * 8 + sc) * 128) * 64 + lane;

    float accA = 0.f, accB = 0.f;
    #pragma unroll 8
    for (int h4 = 0; h4 < 128; ++h4) {
        float4 kb = bp[h4 * 64];
        float4 v4 = *(const float4*)&Vp[h4 * 4];
        float4 qA = *(const float4*)&aA[h4 * 4];
        float4 qB = *(const float4*)&aB[h4 * 4];
        accA = quad_term(qA, kb, v4, accA);
        accB = quad_term(qB, kb, v4, accB);
    }
    const float xA = fmaf(-2.f, accA, pv);
    const float xB = fmaf(-2.f, accB, pv);

    const float eA = EXP2(xA * LOG2E);
    const float eB = EXP2(xB * LOG2E);

    float zA = eA, zB = eB;
    #pragma unroll
    for (int off = 32; off; off >>= 1) {
        zA += __shfl_xor(zA, off);
        zB += __shfl_xor(zB, off);
    }

    // split e -> bf16 hi/lo, coalesced u16 stores
    unsigned uA = __float_as_uint(eA), uB = __float_as_uint(eB);
    unsigned hA = uA & 0xFFFF0000u,   hB = uB & 0xFFFF0000u;
    const size_t rowA = (size_t)(b * T + ta);
    const size_t rowB = (size_t)(b * T + tb);
    e_hi[rowA * S + s0 + lane] = (u16)(hA >> 16);
    e_lo[rowA * S + s0 + lane] = f2bf(eA - __uint_as_float(hA));
    e_hi[rowB * S + s0 + lane] = (u16)(hB >> 16);
    e_lo[rowB * S + s0 + lane] = f2bf(eB - __uint_as_float(hB));

    if (lane == 0) {
        Zp[(size_t)sc * BT + rowA] = zA;
        Zp[(size_t)sc * BT + rowB] = zB;
    }
}

// ---------------------------------------------------------------------------
// K3: context GEMM via MFMA:  out[b][t][h] = (e @ enc)[t][h] / Z[t]
// 64x64 tile, 4 waves, BK=64 — clone of K1's staging/swizzle pattern.
// Grid (8 h-tiles, 4 m-tiles, 4 b) = 128 blocks.
// ---------------------------------------------------------------------------
__global__ __launch_bounds__(256) void ctx_mfma(
    const u16* __restrict__ e_hi, const u16* __restrict__ e_lo,
    const u16* __restrict__ eT_hi, const u16* __restrict__ eT_lo,
    const float* __restrict__ Zp, float* __restrict__ out)
{
    __shared__ u16 lds[4 * 4096];
    __shared__ float zinv[64];

    const int tid  = threadIdx.x;
    const int lane = tid & 63;
    const int w    = tid >> 6;
    const int n0   = blockIdx.x * 64;     // h
    const int m0   = blockIdx.y * 64;     // t within batch
    const int b    = blockIdx.z;

    if (tid < 64) {
        float z = 0.f;
        #pragma unroll
        for (int c = 0; c < 8; ++c) z += Zp[(size_t)c * BT + b * T + m0 + tid];
        zinv[tid] = __builtin_amdgcn_rcpf(z);
    }

    const int wm = (w & 1) * 32;
    const int wn = (w >> 1) * 32;
    const int r0  = tid >> 3;
    const int kc0 = tid & 7;

    const size_t abase = (size_t)(b * T + m0);
    const size_t bbase = (size_t)b * H + n0;

    f32x4 acc[2][2] = {};

    for (int kb = 0; kb < 8; ++kb) {
        const int k0 = kb * 64 + kc0 * 8;
        const size_t ga0 = (abase + r0) * S + k0;
        const size_t ga1 = (abase + r0 + 32) * S + k0;
        const size_t gw0 = (bbase + r0) * S + k0;
        const size_t gw1 = (bbase + r0 + 32) * S + k0;
        bf16x8 ah0 = *(const bf16x8*)&e_hi[ga0];
        bf16x8 ah1 = *(const bf16x8*)&e_hi[ga1];
        bf16x8 al0 = *(const bf16x8*)&e_lo[ga0];
        bf16x8 al1 = *(const bf16x8*)&e_lo[ga1];
        bf16x8 wh0 = *(const bf16x8*)&eT_hi[gw0];
        bf16x8 wh1 = *(const bf16x8*)&eT_hi[gw1];
        bf16x8 wl0 = *(const bf16x8*)&eT_lo[gw0];
        bf16x8 wl1 = *(const bf16x8*)&eT_lo[gw1];
        __syncthreads();
        const int sw  = (kc0 ^ (r0 & 7)) << 3;
        const int s0o = r0 * 64 + sw;
        const int s1o = (r0 + 32) * 64 + sw;
        *(bf16x8*)&lds[0 * 4096 + s0o] = ah0;  *(bf16x8*)&lds[0 * 4096 + s1o] = ah1;
        *(bf16x8*)&lds[1 * 4096 + s0o] = al0;  *(bf16x8*)&lds[1 * 4096 + s1o] = al1;
        *(bf16x8*)&lds[2 * 4096 + s0o] = wh0;  *(bf16x8*)&lds[2 * 4096 + s1o] = wh1;
        *(bf16x8*)&lds[3 * 4096 + s0o] = wl0;  *(bf16x8*)&lds[3 * 4096 + s1o] = wl1;
        __syncthreads();

        #pragma unroll
        for (int ks = 0; ks < 2; ++ks) {
            const int kg = ks * 4 + (lane >> 4);
            bf16x8 amh[2], aml[2], bnh[2], bnl[2];
            #pragma unroll
            for (int ms = 0; ms < 2; ++ms) {
                const int row = wm + ms * 16 + (lane & 15);
                const int off = row * 64 + ((kg ^ (row & 7)) << 3);
                amh[ms] = *(const bf16x8*)&lds[0 * 4096 + off];
                aml[ms] = *(const bf16x8*)&lds[1 * 4096 + off];
            }
            #pragma unroll
            for (int ns = 0; ns < 2; ++ns) {
                const int row = wn + ns * 16 + (lane & 15);
                const int off = row * 64 + ((kg ^ (row & 7)) << 3);
                bnh[ns] = *(const bf16x8*)&lds[2 * 4096 + off];
                bnl[ns] = *(const bf16x8*)&lds[3 * 4096 + off];
            }
            #pragma unroll
            for (int ms = 0; ms < 2; ++ms)
                #pragma unroll
                for (int ns = 0; ns < 2; ++ns) {
                    acc[ms][ns] = __builtin_amdgcn_mfma_f32_16x16x32_bf16(amh[ms], bnh[ns], acc[ms][ns], 0, 0, 0);
                    acc[ms][ns] = __builtin_amdgcn_mfma_f32_16x16x32_bf16(amh[ms], bnl[ns], acc[ms][ns], 0, 0, 0);
                    acc[ms][ns] = __builtin_amdgcn_mfma_f32_16x16x32_bf16(aml[ms], bnh[ns], acc[ms][ns], 0, 0, 0);
                }
        }
    }

    #pragma unroll
    for (int ns = 0; ns < 2; ++ns) {
        const int col = n0 + wn + ns * 16 + (lane & 15);
        #pragma unroll
        for (int ms = 0; ms < 2; ++ms) {
            #pragma unroll
            for (int r = 0; r < 4; ++r) {
                const int row = wm + ms * 16 + (lane >> 4) * 4 + r;
                out[((size_t)(b * T + m0 + row)) * H + col] = acc[ms][ns][r] * zinv[row];
            }
        }
    }
}

extern "C" void kernel_launch(void* const* d_in, const int* in_sizes, int n_in,
                              void* d_out, int out_size, void* d_ws, size_t ws_size,
                              hipStream_t stream) {
    const float* dh  = (const float*)d_in[0];
    const float* enc = (const float*)d_in[1];
    const float* W1  = (const float*)d_in[2];
    const float* b1  = (const float*)d_in[3];
    const float* W2  = (const float*)d_in[4];
    const float* b2  = (const float*)d_in[5];
    const float* V   = (const float*)d_in[6];
    const float* bV  = (const float*)d_in[7];

    float* abuf   = (float*)d_ws;                       // B*T*H f32 = 2 MB
    float* bT4    = abuf + (size_t)B * T * H;           // B*S*H f32 = 4 MB
    u16*  encT_hi = (u16*)(bT4 + (size_t)B * S * H);    // B*H*S u16 = 2 MB
    u16*  encT_lo = encT_hi + (size_t)B * H * S;        // 2 MB
    u16*  e_hi    = encT_lo + (size_t)B * H * S;        // B*T*S u16 = 1 MB
    u16*  e_lo    = e_hi + (size_t)B * T * S;           // 1 MB
    float* Zp     = (float*)(e_lo + (size_t)B * T * S); // 8*BT f32 = 32 KB

    mfma_proj<<<dim3(8, 80),    dim3(256), 0, stream>>>(dh, enc, W1, W2, b1, b2,
                                                        abuf, bT4, encT_hi, encT_lo);
    score_e  <<<dim3(8, 16, 4), dim3(512), 0, stream>>>(abuf, bT4, V, bV, e_hi, e_lo, Zp);
    ctx_mfma <<<dim3(8, 4, 4),  dim3(256), 0, stream>>>(e_hi, e_lo, encT_hi, encT_lo,
                                                        Zp, (float*)d_out);
}